// Round 7
// baseline (785.762 us; speedup 1.0000x reference)
//
#include <hip/hip_runtime.h>
#include <hip/hip_bf16.h>
#include <cstdint>
#include <cstddef>

#define B_ 8
#define C_ 2048
#define F_ 512
#define TTILES 32            // C_/64
#define NPAIRS 528           // TTILES*(TTILES+1)/2
#define BAND 0.015f
#define FLAGCAP (1u << 18)

typedef short bf16x8 __attribute__((ext_vector_type(8)));
typedef float f32x4 __attribute__((ext_vector_type(4)));

// ---------------------------------------------------------------------------
// ws layout (bytes):
//   nrm   double[16384]      @ 0          131072
//   bits  uint32[16384*64]   @ 131072     4194304
//   sinv  float[16384]       @ 4325376    65536
//   flagn uint32             @ 4390912    256
//   flags uint32[256K]       @ 4391168    1048576
//   wt    ushort[4*256K]     @ 5439744    2097152   (W1hi,W1lo,W2hi,W2lo; [n][k])
//   xhi   ushort[8M]         @ 7536896    16777216  (later reused as h1hi)
//   xlo   ushort[8M]         @ 24314112   16777216  (later reused as h1lo)
//   gthi  ushort[8M]         @ 41091328   16777216  (v^T hi, [b][f][d])
//   gtlo  ushort[8M]         @ 57868544   16777216
// total 74.6 MB
// ---------------------------------------------------------------------------

__device__ __forceinline__ ushort bf16hi(float v) {
  return __builtin_bit_cast(unsigned short, __float2bfloat16(v));
}

__global__ __launch_bounds__(64) void kzero1(uint32_t* __restrict__ flagn) {
  if (threadIdx.x == 0) *flagn = 0u;
}

__global__ __launch_bounds__(256) void ksplit(const float* __restrict__ x,
                                              ushort* __restrict__ xhi,
                                              ushort* __restrict__ xlo) {
  size_t i = ((size_t)blockIdx.x * 256 + threadIdx.x) * 8;
  float4 v0 = *reinterpret_cast<const float4*>(x + i);
  float4 v1 = *reinterpret_cast<const float4*>(x + i + 4);
  float vv[8] = {v0.x, v0.y, v0.z, v0.w, v1.x, v1.y, v1.z, v1.w};
  ushort h[8], lo[8];
#pragma unroll
  for (int j = 0; j < 8; ++j) {
    ushort hh = bf16hi(vv[j]);
    float hf = __bfloat162float(__builtin_bit_cast(__hip_bfloat16, hh));
    h[j] = hh; lo[j] = bf16hi(vv[j] - hf);
  }
  *reinterpret_cast<uint4*>(xhi + i) = *reinterpret_cast<uint4*>(h);
  *reinterpret_cast<uint4*>(xlo + i) = *reinterpret_cast<uint4*>(lo);
}

__global__ __launch_bounds__(256) void kwsplit(const float* __restrict__ W1,
                                               const float* __restrict__ W2,
                                               ushort* __restrict__ wtbuf) {
  const float* W = blockIdx.z ? W2 : W1;
  ushort* whi = wtbuf + (size_t)blockIdx.z * 524288;
  ushort* wlo = whi + 262144;
  int k0 = blockIdx.x * 64, n0 = blockIdx.y * 64, tid = threadIdx.x;
  __shared__ float t[64][65];
#pragma unroll
  for (int it = 0; it < 4; ++it) {
    int slot = tid + it * 256;
    int row = slot >> 4, c4 = slot & 15;
    float4 v = *reinterpret_cast<const float4*>(&W[(size_t)(k0 + row) * 512 + n0 + c4 * 4]);
    t[row][c4 * 4 + 0] = v.x; t[row][c4 * 4 + 1] = v.y;
    t[row][c4 * 4 + 2] = v.z; t[row][c4 * 4 + 3] = v.w;
  }
  __syncthreads();
#pragma unroll
  for (int it = 0; it < 2; ++it) {
    int slot = tid + it * 256;
    int n = slot >> 3, g = slot & 7;
    ushort h8[8], l8[8];
#pragma unroll
    for (int j = 0; j < 8; ++j) {
      float v = t[g * 8 + j][n];
      ushort hh = bf16hi(v);
      float hf = __bfloat162float(__builtin_bit_cast(__hip_bfloat16, hh));
      h8[j] = hh; l8[j] = bf16hi(v - hf);
    }
    size_t ga = (size_t)(n0 + n) * 512 + k0 + g * 8;
    *reinterpret_cast<uint4*>(&whi[ga]) = *reinterpret_cast<uint4*>(h8);
    *reinterpret_cast<uint4*>(&wlo[ga]) = *reinterpret_cast<uint4*>(l8);
  }
}

__global__ __launch_bounds__(256) void knorm(const float* __restrict__ x,
                                             double* __restrict__ nrm) {
  int row = blockIdx.x * 4 + (threadIdx.x >> 6);
  int lane = threadIdx.x & 63;
  const float4* xr = reinterpret_cast<const float4*>(x + (size_t)row * F_);
  float4 v1 = xr[lane];
  float4 v2 = xr[lane + 64];
  double s = (double)v1.x * v1.x + (double)v1.y * v1.y +
             (double)v1.z * v1.z + (double)v1.w * v1.w +
             (double)v2.x * v2.x + (double)v2.y * v2.y +
             (double)v2.z * v2.z + (double)v2.w * v2.w;
#pragma unroll
  for (int off = 32; off > 0; off >>= 1) s += __shfl_down(s, off, 64);
  if (lane == 0) nrm[row] = sqrt(s);
}

// ---- bf16-MFMA Gram, reg-prefetch pipelined, binarize + band-flag ----
__global__ __launch_bounds__(256) void kgram2(const ushort* __restrict__ xhi,
                                              const ushort* __restrict__ xlo,
                                              const double* __restrict__ nrm,
                                              uint32_t* __restrict__ bits,
                                              uint32_t* __restrict__ flagn,
                                              uint32_t* __restrict__ flags) {
  int flat = (int)blockIdx.x;
  int b = flat & 7;                 // XCD k handles batch k
  int tt = flat >> 3, I = 0;
  while (tt >= TTILES - I) { tt -= TTILES - I; ++I; }
  int J = I + tt;
  bool offdiag = (I != J);
  int c0 = I * 64, d0 = J * 64;
  int tid = threadIdx.x;
  int l = tid & 63, w = tid >> 6;
  int wc = w >> 1, wf = w & 1;
  int lg = l >> 4, li = l & 15;

  __shared__ ushort sm[4 * 64 * 64];
  __shared__ uint32_t lb[64][2];
  __shared__ uint32_t lbT[64][2];

  f32x4 acc[2][2];
#pragma unroll
  for (int m = 0; m < 2; ++m)
#pragma unroll
    for (int n = 0; n < 2; ++n) acc[m][n] = (f32x4){0.f, 0.f, 0.f, 0.f};

  const size_t xbase = (size_t)b * C_ * F_;

  // per-thread staging descriptors
  const ushort* gs[8]; int lo8[8];
#pragma unroll
  for (int s = 0; s < 8; ++s) {
    int is = w + s * 4;
    int tile = is >> 3, sub = is & 7;
    const ushort* src = (tile & 1) ? xlo : xhi;
    int rbase = (tile < 2) ? c0 : d0;
    int row = sub * 8 + (l >> 3);
    int g = l & 7;
    gs[s] = src + xbase + (size_t)(rbase + row) * F_ + g * 8;
    lo8[s] = tile * 4096 + row * 64 + ((g ^ (row & 7)) * 8);
  }

  uint4 rX[2][8];
#pragma unroll
  for (int s = 0; s < 8; ++s) rX[0][s] = *reinterpret_cast<const uint4*>(gs[s]);

#pragma unroll
  for (int kc = 0; kc < 8; ++kc) {
    int cur = kc & 1;
    __builtin_amdgcn_sched_barrier(0);
    __builtin_amdgcn_s_barrier();                 // B1: prev MFMA reads done
#pragma unroll
    for (int s = 0; s < 8; ++s)
      *reinterpret_cast<uint4*>(&sm[lo8[s]]) = rX[cur][s];
#pragma unroll
    for (int s = 0; s < 8; ++s)
      rX[cur ^ 1][s] = *reinterpret_cast<const uint4*>(gs[s] + ((kc + 1) & 7) * 64);
    asm volatile("s_waitcnt lgkmcnt(0)" ::: "memory");
    __builtin_amdgcn_sched_barrier(0);
    __builtin_amdgcn_s_barrier();                 // B2: LDS visible
#pragma unroll
    for (int kk = 0; kk < 2; ++kk) {
      bf16x8 ah[2], al[2], bh[2], bl[2];
#pragma unroll
      for (int m = 0; m < 2; ++m) {
        int row = wc * 32 + m * 16 + li;
        int off = row * 64 + (((kk * 4 + lg) ^ (row & 7)) * 8);
        ah[m] = *reinterpret_cast<const bf16x8*>(&sm[off]);
        al[m] = *reinterpret_cast<const bf16x8*>(&sm[4096 + off]);
      }
#pragma unroll
      for (int n = 0; n < 2; ++n) {
        int row = wf * 32 + n * 16 + li;
        int off = row * 64 + (((kk * 4 + lg) ^ (row & 7)) * 8);
        bh[n] = *reinterpret_cast<const bf16x8*>(&sm[8192 + off]);
        bl[n] = *reinterpret_cast<const bf16x8*>(&sm[12288 + off]);
      }
#pragma unroll
      for (int m = 0; m < 2; ++m)
#pragma unroll
        for (int n = 0; n < 2; ++n) {
          acc[m][n] = __builtin_amdgcn_mfma_f32_16x16x32_bf16(ah[m], bh[n], acc[m][n], 0, 0, 0);
          acc[m][n] = __builtin_amdgcn_mfma_f32_16x16x32_bf16(ah[m], bl[n], acc[m][n], 0, 0, 0);
          acc[m][n] = __builtin_amdgcn_mfma_f32_16x16x32_bf16(al[m], bh[n], acc[m][n], 0, 0, 0);
        }
    }
  }

  double ncv[2][4], ndv[2];
#pragma unroll
  for (int m = 0; m < 2; ++m)
#pragma unroll
    for (int q = 0; q < 4; ++q)
      ncv[m][q] = nrm[b * C_ + c0 + wc * 32 + m * 16 + lg * 4 + q];
#pragma unroll
  for (int n = 0; n < 2; ++n)
    ndv[n] = nrm[b * C_ + d0 + wf * 32 + n * 16 + li];

#pragma unroll
  for (int m = 0; m < 2; ++m) {
#pragma unroll
    for (int q = 0; q < 4; ++q) {
      uint32_t wv = 0;
#pragma unroll
      for (int n = 0; n < 2; ++n) {
        float num = acc[m][n][q];
        float tq = (float)(0.005 * ncv[m][q] * ndv[n]);
        bool bit = num > tq;
        if (fabsf(num - tq) < BAND) {
          uint32_t idx = atomicAdd(flagn, 1u);
          if (idx < FLAGCAP) {
            int cc = c0 + wc * 32 + m * 16 + lg * 4 + q;
            int dd = d0 + wf * 32 + n * 16 + li;
            flags[idx] = ((uint32_t)b << 22) | ((uint32_t)cc << 11) | (uint32_t)dd;
          }
        }
        unsigned long long bal = __ballot(bit);
        uint32_t b16 = (uint32_t)((bal >> (lg * 16)) & 0xFFFFull);
        wv |= b16 << (n * 16);
      }
      if (li == 0) lb[wc * 32 + m * 16 + lg * 4 + q][wf] = wv;
    }
  }
  __syncthreads();
  if (offdiag && tid < 64) {
    uint32_t w0 = 0, w1 = 0;
    int word = tid >> 5, sh = tid & 31;
    for (int c = 0; c < 32; ++c)  w0 |= ((lb[c][word] >> sh) & 1u) << c;
    for (int c = 32; c < 64; ++c) w1 |= ((lb[c][word] >> sh) & 1u) << (c - 32);
    lbT[tid][0] = w0; lbT[tid][1] = w1;
  }
  __syncthreads();
  if (tid < 64) {
    size_t base = ((size_t)b * C_ + c0 + tid) * 64 + (size_t)J * 2;
    bits[base] = lb[tid][0]; bits[base + 1] = lb[tid][1];
  } else if (offdiag && tid < 128) {
    int r = tid - 64;
    size_t base = ((size_t)b * C_ + d0 + r) * 64 + (size_t)I * 2;
    bits[base] = lbT[r][0]; bits[base + 1] = lbT[r][1];
  }
}

__global__ __launch_bounds__(256) void krepair(const float* __restrict__ x,
                                               const double* __restrict__ nrm,
                                               const uint32_t* __restrict__ flagn,
                                               const uint32_t* __restrict__ flags,
                                               uint32_t* __restrict__ bits) {
  int l = threadIdx.x & 63;
  uint32_t wave = (blockIdx.x * 256 + threadIdx.x) >> 6;
  uint32_t nwaves = (gridDim.x * 256) >> 6;
  uint32_t nf = *flagn; if (nf > FLAGCAP) nf = FLAGCAP;
  for (uint32_t p = wave; p < nf; p += nwaves) {
    uint32_t e = flags[p];
    int b = e >> 22, c = (e >> 11) & 2047, d = e & 2047;
    const float* xc = x + ((size_t)b * C_ + c) * F_;
    const float* xd = x + ((size_t)b * C_ + d) * F_;
    double s = 0.0;
#pragma unroll
    for (int j = 0; j < 8; ++j) {
      int k = l * 8 + j;
      s += (double)xc[k] * (double)xd[k];
    }
#pragma unroll
    for (int off = 32; off > 0; off >>= 1) s += __shfl_down(s, off, 64);
    if (l == 0) {
      bool bit = s > 0.005 * nrm[b * C_ + c] * nrm[b * C_ + d];
      uint32_t* wcd = bits + (((size_t)b * C_ + c) << 6) + (d >> 5);
      uint32_t* wdc = bits + (((size_t)b * C_ + d) << 6) + (c >> 5);
      uint32_t mcd = 1u << (d & 31), mdc = 1u << (c & 31);
      if (bit) { atomicOr(wcd, mcd);  atomicOr(wdc, mdc); }
      else     { atomicAnd(wcd, ~mcd); atomicAnd(wdc, ~mdc); }
    }
  }
}

__global__ __launch_bounds__(256) void kdeg(const uint32_t* __restrict__ bits,
                                            float* __restrict__ sinv) {
  int row = blockIdx.x * 256 + threadIdx.x;
  const uint4* p = reinterpret_cast<const uint4*>(bits + ((size_t)row << 6));
  uint32_t s = 0;
#pragma unroll
  for (int i = 0; i < 16; ++i) {
    uint4 v = p[i];
    s += __popc(v.x) + __popc(v.y) + __popc(v.z) + __popc(v.w);
  }
  sinv[row] = 1.0f / sqrtf((float)s);
}

// ---- split-bf16 MFMA GEMM, pipelined, LDS-transposed coalesced gT output ----
__global__ __launch_bounds__(256) void kgemm_mfma(const ushort* __restrict__ ahi,
                                                  const ushort* __restrict__ alo,
                                                  const ushort* __restrict__ wthi,
                                                  const ushort* __restrict__ wtlo,
                                                  const float* __restrict__ sinv,
                                                  ushort* __restrict__ gthi,
                                                  ushort* __restrict__ gtlo) {
  int flat = (int)blockIdx.x;
  int b = flat & 7, rest = flat >> 3;
  int mtl = rest & 31, nt = rest >> 5;
  int m0 = b * C_ + mtl * 64;        // global row (d-channel)
  int n0 = nt * 64;                  // f
  int tid = threadIdx.x;
  int l = tid & 63, w = tid >> 6;
  int wc = w >> 1, wf = w & 1;
  int lg = l >> 4, li = l & 15;

  __shared__ ushort smem[16384];     // Ahi|Alo|Whi|Wlo @ 0/4096/8192/12288

  int ldso[2];
  const ushort* gA[2][2]; const ushort* gW[2][2];
#pragma unroll
  for (int it = 0; it < 2; ++it) {
    int slot = tid + it * 256, row = slot >> 3, grp = slot & 7;
    ldso[it] = row * 64 + ((grp ^ (row & 7)) * 8);
    size_t ga = (size_t)(m0 + row) * 512 + grp * 8;
    gA[it][0] = ahi + ga; gA[it][1] = alo + ga;
    size_t gw = (size_t)(n0 + row) * 512 + grp * 8;
    gW[it][0] = wthi + gw; gW[it][1] = wtlo + gw;
  }

  f32x4 acc[2][2];
#pragma unroll
  for (int m = 0; m < 2; ++m)
#pragma unroll
    for (int n = 0; n < 2; ++n) acc[m][n] = (f32x4){0.f, 0.f, 0.f, 0.f};

  uint4 rA[2][2][2];
#pragma unroll
  for (int it = 0; it < 2; ++it) {
    rA[0][it][0] = *reinterpret_cast<const uint4*>(gA[it][0]);
    rA[0][it][1] = *reinterpret_cast<const uint4*>(gA[it][1]);
  }

#pragma unroll
  for (int kc = 0; kc < 8; ++kc) {
    int cur = kc & 1;
    int k0 = kc * 64;
    __builtin_amdgcn_sched_barrier(0);
    __builtin_amdgcn_s_barrier();
#pragma unroll
    for (int it = 0; it < 2; ++it) {
      *reinterpret_cast<uint4*>(&smem[ldso[it]])        = rA[cur][it][0];
      *reinterpret_cast<uint4*>(&smem[4096 + ldso[it]]) = rA[cur][it][1];
    }
#pragma unroll
    for (int it = 0; it < 2; ++it) {
      int nk = ((kc + 1) & 7) * 64;
      rA[cur ^ 1][it][0] = *reinterpret_cast<const uint4*>(gA[it][0] + nk);
      rA[cur ^ 1][it][1] = *reinterpret_cast<const uint4*>(gA[it][1] + nk);
    }
#pragma unroll
    for (int it = 0; it < 2; ++it) {
      *reinterpret_cast<uint4*>(&smem[8192 + ldso[it]])  = *reinterpret_cast<const uint4*>(gW[it][0] + k0);
      *reinterpret_cast<uint4*>(&smem[12288 + ldso[it]]) = *reinterpret_cast<const uint4*>(gW[it][1] + k0);
    }
    asm volatile("s_waitcnt lgkmcnt(0)" ::: "memory");
    __builtin_amdgcn_sched_barrier(0);
    __builtin_amdgcn_s_barrier();
#pragma unroll
    for (int kk = 0; kk < 2; ++kk) {
      bf16x8 ah[2], al[2], wh[2], wl[2];
#pragma unroll
      for (int m = 0; m < 2; ++m) {
        int row = wc * 32 + m * 16 + li;
        int off = row * 64 + (((kk * 4 + lg) ^ (row & 7)) * 8);
        ah[m] = *reinterpret_cast<const bf16x8*>(&smem[off]);
        al[m] = *reinterpret_cast<const bf16x8*>(&smem[4096 + off]);
      }
#pragma unroll
      for (int n = 0; n < 2; ++n) {
        int row = wf * 32 + n * 16 + li;
        int off = row * 64 + (((kk * 4 + lg) ^ (row & 7)) * 8);
        wh[n] = *reinterpret_cast<const bf16x8*>(&smem[8192 + off]);
        wl[n] = *reinterpret_cast<const bf16x8*>(&smem[12288 + off]);
      }
#pragma unroll
      for (int m = 0; m < 2; ++m)
#pragma unroll
        for (int n = 0; n < 2; ++n) {
          acc[m][n] = __builtin_amdgcn_mfma_f32_16x16x32_bf16(ah[m], wh[n], acc[m][n], 0, 0, 0);
          acc[m][n] = __builtin_amdgcn_mfma_f32_16x16x32_bf16(ah[m], wl[n], acc[m][n], 0, 0, 0);
          acc[m][n] = __builtin_amdgcn_mfma_f32_16x16x32_bf16(al[m], wh[n], acc[m][n], 0, 0, 0);
          acc[m][n] = __builtin_amdgcn_mfma_f32_16x16x32_bf16(al[m], wl[n], acc[m][n], 0, 0, 0);
        }
    }
  }

  // epilogue: apply sinv, split, transpose via LDS, coalesced gT writes
  __syncthreads();
#pragma unroll
  for (int m = 0; m < 2; ++m) {
    int dl = wc * 32 + m * 16 + lg * 4;
    f32x4 sc = *reinterpret_cast<const f32x4*>(&sinv[m0 + dl]);
#pragma unroll
    for (int n = 0; n < 2; ++n) {
      int fl = wf * 32 + n * 16 + li;
      ushort h4[4], l4[4];
#pragma unroll
      for (int q = 0; q < 4; ++q) {
        float v = sc[q] * acc[m][n][q];
        ushort hh = bf16hi(v);
        float hf = __bfloat162float(__builtin_bit_cast(__hip_bfloat16, hh));
        h4[q] = hh; l4[q] = bf16hi(v - hf);
      }
      *reinterpret_cast<ushort4*>(&smem[fl * 68 + dl])        = *reinterpret_cast<ushort4*>(h4);
      *reinterpret_cast<ushort4*>(&smem[4352 + fl * 68 + dl]) = *reinterpret_cast<ushort4*>(l4);
    }
  }
  __syncthreads();
  {
    int fl = tid >> 2, seg = tid & 3;
    int cb = mtl * 64;
    int lo = fl * 68 + seg * 16;
    size_t ga = ((size_t)b * F_ + n0 + fl) * C_ + cb + seg * 16;
    uint4 p0 = *reinterpret_cast<const uint4*>(&smem[lo]);
    uint4 p1 = *reinterpret_cast<const uint4*>(&smem[lo + 8]);
    *reinterpret_cast<uint4*>(&gthi[ga])     = p0;
    *reinterpret_cast<uint4*>(&gthi[ga + 8]) = p1;
    uint4 q0 = *reinterpret_cast<const uint4*>(&smem[4352 + lo]);
    uint4 q1 = *reinterpret_cast<const uint4*>(&smem[4352 + lo + 8]);
    *reinterpret_cast<uint4*>(&gtlo[ga])     = q0;
    *reinterpret_cast<uint4*>(&gtlo[ga + 8]) = q1;
  }
}

// ---- MFMA propagation, 128c x 64f tile, pipelined ----
#define PROP_CHUNK(D, USE, PF, DN)                                            \
  {                                                                           \
    __builtin_amdgcn_sched_barrier(0);                                        \
    __builtin_amdgcn_s_barrier();                                             \
    _Pragma("unroll")                                                         \
    for (int it = 0; it < 2; ++it) {                                          \
      *reinterpret_cast<uint4*>(&smv[ldso[it]])        = USE[it][0];          \
      *reinterpret_cast<uint4*>(&smv[4096 + ldso[it]]) = USE[it][1];          \
    }                                                                         \
    _Pragma("unroll")                                                         \
    for (int it = 0; it < 2; ++it) {                                          \
      PF[it][0] = *reinterpret_cast<const uint4*>(gsh[it] + (DN));            \
      PF[it][1] = *reinterpret_cast<const uint4*>(gsl[it] + (DN));            \
    }                                                                         \
    asm volatile("s_waitcnt lgkmcnt(0)" ::: "memory");                        \
    __builtin_amdgcn_sched_barrier(0);                                        \
    __builtin_amdgcn_s_barrier();                                             \
    int wbase = (D) >> 5;                                                     \
    _Pragma("unroll")                                                         \
    for (int kk = 0; kk < 2; ++kk) {                                          \
      uint32_t wd0 = blds[w32 + li][wbase + kk];                              \
      uint32_t wd1 = blds[w32 + 16 + li][wbase + kk];                         \
      uint32_t by0 = (wd0 >> (lg * 8)) & 0xFFu;                               \
      uint32_t by1 = (wd1 >> (lg * 8)) & 0xFFu;                               \
      bf16x8 a0, a1;                                                          \
      _Pragma("unroll")                                                       \
      for (int j = 0; j < 8; ++j) {                                           \
        a0[j] = (short)(((by0 >> j) & 1u) ? 0x3F80 : 0);                      \
        a1[j] = (short)(((by1 >> j) & 1u) ? 0x3F80 : 0);                      \
      }                                                                       \
      _Pragma("unroll")                                                       \
      for (int n = 0; n < 4; ++n) {                                           \
        int row = n * 16 + li;                                                \
        int off = row * 64 + (((kk * 4 + lg) ^ (row & 7)) * 8);               \
        bf16x8 bh = *reinterpret_cast<const bf16x8*>(&smv[off]);              \
        bf16x8 bl = *reinterpret_cast<const bf16x8*>(&smv[4096 + off]);       \
        acc[0][n] = __builtin_amdgcn_mfma_f32_16x16x32_bf16(a0, bh, acc[0][n], 0, 0, 0); \
        acc[0][n] = __builtin_amdgcn_mfma_f32_16x16x32_bf16(a0, bl, acc[0][n], 0, 0, 0); \
        acc[1][n] = __builtin_amdgcn_mfma_f32_16x16x32_bf16(a1, bh, acc[1][n], 0, 0, 0); \
        acc[1][n] = __builtin_amdgcn_mfma_f32_16x16x32_bf16(a1, bl, acc[1][n], 0, 0, 0); \
      }                                                                       \
    }                                                                         \
  }

__global__ __launch_bounds__(256) void kprop_mfma(const ushort* __restrict__ gthi,
                                                  const ushort* __restrict__ gtlo,
                                                  const float* __restrict__ sinv,
                                                  const uint32_t* __restrict__ bits,
                                                  const float* __restrict__ bias,
                                                  ushort* __restrict__ ohi,
                                                  ushort* __restrict__ olo,
                                                  float* __restrict__ of32) {
  int flat = (int)blockIdx.x;
  int b = flat & 7, rest = flat >> 3;
  int ct = rest & 15, ft = rest >> 4;
  int c0 = ct * 128, f0 = ft * 64;
  int tid = threadIdx.x;
  int l = tid & 63, w = tid >> 6;      // wave w -> c rows [c0+w*32, +32)
  int lg = l >> 4, li = l & 15;
  int w32 = w * 32;

  __shared__ ushort smv[8192];         // vThi | vTlo (4096 each), swizzled [f][d]
  __shared__ uint32_t blds[128][68];

  // bits -> LDS: 128 rows x 64 words
  const uint32_t* bp = bits + (((size_t)b * C_ + c0) << 6);
#pragma unroll
  for (int t = 0; t < 8; ++t) {
    int gi = (t * 256 + tid) * 4;
    uint4 q = *reinterpret_cast<const uint4*>(bp + gi);
    int row = gi >> 6, col = gi & 63;
    *reinterpret_cast<uint4*>(&blds[row][col]) = q;
  }

  int ldso[2];
  const ushort* gsh[2]; const ushort* gsl[2];
#pragma unroll
  for (int it = 0; it < 2; ++it) {
    int s = tid + it * 256, row = s >> 3, grp = s & 7;
    ldso[it] = row * 64 + ((grp ^ (row & 7)) * 8);
    size_t ga = ((size_t)b * F_ + f0 + row) * (size_t)C_ + grp * 8;
    gsh[it] = gthi + ga; gsl[it] = gtlo + ga;
  }

  f32x4 acc[2][4];
#pragma unroll
  for (int m = 0; m < 2; ++m)
#pragma unroll
    for (int n = 0; n < 4; ++n) acc[m][n] = (f32x4){0.f, 0.f, 0.f, 0.f};

  uint4 rA[2][2], rB[2][2];
#pragma unroll
  for (int it = 0; it < 2; ++it) {
    rA[it][0] = *reinterpret_cast<const uint4*>(gsh[it]);
    rA[it][1] = *reinterpret_cast<const uint4*>(gsl[it]);
  }

  for (int d0 = 0; d0 < C_; d0 += 128) {
    PROP_CHUNK(d0,      rA, rB, d0 + 64);
    PROP_CHUNK(d0 + 64, rB, rA, (d0 + 128) & (C_ - 1));
  }

  const float* sv = sinv + b * C_;
  float bb = bias[0];
#pragma unroll
  for (int m = 0; m < 2; ++m) {
    int rowb = c0 + w32 + m * 16 + lg * 4;
    f32x4 sc = *reinterpret_cast<const f32x4*>(&sv[rowb]);
#pragma unroll
    for (int n = 0; n < 4; ++n) {
      int col = f0 + n * 16 + li;
      if (of32) {
#pragma unroll
        for (int q = 0; q < 4; ++q) {
          float o = fmaxf(sc[q] * acc[m][n][q] + bb, 0.f);
          of32[((size_t)b * C_ + rowb + q) * F_ + col] = o;
        }
      } else {
#pragma unroll
        for (int q = 0; q < 4; ++q) {
          float o = fmaxf(sc[q] * acc[m][n][q] + bb, 0.f);
          ushort hh = bf16hi(o);
          float hf = __bfloat162float(__builtin_bit_cast(__hip_bfloat16, hh));
          size_t ga = ((size_t)b * C_ + rowb + q) * F_ + col;
          ohi[ga] = hh;
          olo[ga] = bf16hi(o - hf);
        }
      }
    }
  }
}

extern "C" void kernel_launch(void* const* d_in, const int* in_sizes, int n_in,
                              void* d_out, int out_size, void* d_ws, size_t ws_size,
                              hipStream_t stream) {
  (void)in_sizes; (void)n_in; (void)out_size; (void)ws_size;
  const float* x  = (const float*)d_in[0];
  const float* W1 = (const float*)d_in[1];
  const float* b1 = (const float*)d_in[2];
  const float* W2 = (const float*)d_in[3];
  const float* b2 = (const float*)d_in[4];
  float* out = (float*)d_out;

  char* ws = (char*)d_ws;
  double*   nrm   = (double*)(ws);
  uint32_t* bits  = (uint32_t*)(ws + 131072);
  float*    sinv  = (float*)(ws + 4325376);
  uint32_t* flagn = (uint32_t*)(ws + 4390912);
  uint32_t* flags = (uint32_t*)(ws + 4391168);
  ushort*   wt    = (ushort*)(ws + 5439744);
  ushort*   xhi   = (ushort*)(ws + 7536896);
  ushort*   xlo   = (ushort*)(ws + 24314112);
  ushort*   gthi  = (ushort*)(ws + 41091328);
  ushort*   gtlo  = (ushort*)(ws + 57868544);
  ushort*   wt1hi = wt, *wt1lo = wt + 262144, *wt2hi = wt + 524288, *wt2lo = wt + 786432;

  kzero1<<<dim3(1), 64, 0, stream>>>(flagn);
  ksplit<<<dim3(B_ * C_ * F_ / 2048), 256, 0, stream>>>(x, xhi, xlo);
  knorm<<<dim3(B_ * C_ / 4), 256, 0, stream>>>(x, nrm);
  kwsplit<<<dim3(8, 8, 2), 256, 0, stream>>>(W1, W2, wt);
  kgram2<<<dim3(NPAIRS * B_), 256, 0, stream>>>(xhi, xlo, nrm, bits, flagn, flags);
  krepair<<<dim3(256), 256, 0, stream>>>(x, nrm, flagn, flags, bits);
  kdeg<<<dim3(B_ * C_ / 256), 256, 0, stream>>>(bits, sinv);

  // layer 1
  kgemm_mfma<<<dim3(2048), 256, 0, stream>>>(xhi, xlo, wt1hi, wt1lo, sinv, gthi, gtlo);
  kprop_mfma<<<dim3(1024), 256, 0, stream>>>(gthi, gtlo, sinv, bits, b1, xhi, xlo, nullptr);
  // layer 2
  kgemm_mfma<<<dim3(2048), 256, 0, stream>>>(xhi, xlo, wt2hi, wt2lo, sinv, gthi, gtlo);
  kprop_mfma<<<dim3(1024), 256, 0, stream>>>(gthi, gtlo, sinv, bits, b2, nullptr, nullptr, out);
}

// Round 8
// 487.650 us; speedup vs baseline: 1.6113x; 1.6113x over previous
//
#include <hip/hip_runtime.h>
#include <hip/hip_bf16.h>
#include <cstdint>
#include <cstddef>

#define B_ 8
#define C_ 2048
#define F_ 512
#define TTILES 32            // C_/64
#define NPAIRS 528           // TTILES*(TTILES+1)/2
#define BAND 0.015f
#define FLAGCAP (1u << 18)

typedef short bf16x8 __attribute__((ext_vector_type(8)));
typedef float f32x4 __attribute__((ext_vector_type(4)));

// ---------------------------------------------------------------------------
// ws layout (bytes):  (unchanged from round 6)
//   nrm   double[16384]      @ 0          131072
//   bits  uint32[16384*64]   @ 131072     4194304
//   sinv  float[16384]       @ 4325376    65536
//   flagn uint32             @ 4390912    256
//   flags uint32[256K]       @ 4391168    1048576
//   wt    ushort[4*256K]     @ 5439744    2097152
//   xhi   ushort[8M]         @ 7536896    16777216  (reused as h1hi)
//   xlo   ushort[8M]         @ 24314112   16777216  (reused as h1lo)
//   gthi  ushort[8M]         @ 41091328   16777216  (v^T hi, [b][f][d])
//   gtlo  ushort[8M]         @ 57868544   16777216
// ---------------------------------------------------------------------------

__device__ __forceinline__ ushort bf16hi(float v) {
  return __builtin_bit_cast(unsigned short, __float2bfloat16(v));
}

// async global->LDS, 16B per lane; lds base must be wave-uniform (linear dest).
__device__ __forceinline__ void gload16(const void* g, void* l) {
  __builtin_amdgcn_global_load_lds(
      (const __attribute__((address_space(1))) void*)g,
      (__attribute__((address_space(3))) void*)l, 16, 0, 0);
}

__global__ __launch_bounds__(64) void kzero1(uint32_t* __restrict__ flagn) {
  if (threadIdx.x == 0) *flagn = 0u;
}

__global__ __launch_bounds__(256) void ksplit(const float* __restrict__ x,
                                              ushort* __restrict__ xhi,
                                              ushort* __restrict__ xlo) {
  size_t i = ((size_t)blockIdx.x * 256 + threadIdx.x) * 8;
  float4 v0 = *reinterpret_cast<const float4*>(x + i);
  float4 v1 = *reinterpret_cast<const float4*>(x + i + 4);
  float vv[8] = {v0.x, v0.y, v0.z, v0.w, v1.x, v1.y, v1.z, v1.w};
  ushort h[8], lo[8];
#pragma unroll
  for (int j = 0; j < 8; ++j) {
    ushort hh = bf16hi(vv[j]);
    float hf = __bfloat162float(__builtin_bit_cast(__hip_bfloat16, hh));
    h[j] = hh; lo[j] = bf16hi(vv[j] - hf);
  }
  *reinterpret_cast<uint4*>(xhi + i) = *reinterpret_cast<uint4*>(h);
  *reinterpret_cast<uint4*>(xlo + i) = *reinterpret_cast<uint4*>(lo);
}

__global__ __launch_bounds__(256) void kwsplit(const float* __restrict__ W1,
                                               const float* __restrict__ W2,
                                               ushort* __restrict__ wtbuf) {
  const float* W = blockIdx.z ? W2 : W1;
  ushort* whi = wtbuf + (size_t)blockIdx.z * 524288;
  ushort* wlo = whi + 262144;
  int k0 = blockIdx.x * 64, n0 = blockIdx.y * 64, tid = threadIdx.x;
  __shared__ float t[64][65];
#pragma unroll
  for (int it = 0; it < 4; ++it) {
    int slot = tid + it * 256;
    int row = slot >> 4, c4 = slot & 15;
    float4 v = *reinterpret_cast<const float4*>(&W[(size_t)(k0 + row) * 512 + n0 + c4 * 4]);
    t[row][c4 * 4 + 0] = v.x; t[row][c4 * 4 + 1] = v.y;
    t[row][c4 * 4 + 2] = v.z; t[row][c4 * 4 + 3] = v.w;
  }
  __syncthreads();
#pragma unroll
  for (int it = 0; it < 2; ++it) {
    int slot = tid + it * 256;
    int n = slot >> 3, g = slot & 7;
    ushort h8[8], l8[8];
#pragma unroll
    for (int j = 0; j < 8; ++j) {
      float v = t[g * 8 + j][n];
      ushort hh = bf16hi(v);
      float hf = __bfloat162float(__builtin_bit_cast(__hip_bfloat16, hh));
      h8[j] = hh; l8[j] = bf16hi(v - hf);
    }
    size_t ga = (size_t)(n0 + n) * 512 + k0 + g * 8;
    *reinterpret_cast<uint4*>(&whi[ga]) = *reinterpret_cast<uint4*>(h8);
    *reinterpret_cast<uint4*>(&wlo[ga]) = *reinterpret_cast<uint4*>(l8);
  }
}

__global__ __launch_bounds__(256) void knorm(const float* __restrict__ x,
                                             double* __restrict__ nrm) {
  int row = blockIdx.x * 4 + (threadIdx.x >> 6);
  int lane = threadIdx.x & 63;
  const float4* xr = reinterpret_cast<const float4*>(x + (size_t)row * F_);
  float4 v1 = xr[lane];
  float4 v2 = xr[lane + 64];
  double s = (double)v1.x * v1.x + (double)v1.y * v1.y +
             (double)v1.z * v1.z + (double)v1.w * v1.w +
             (double)v2.x * v2.x + (double)v2.y * v2.y +
             (double)v2.z * v2.z + (double)v2.w * v2.w;
#pragma unroll
  for (int off = 32; off > 0; off >>= 1) s += __shfl_down(s, off, 64);
  if (lane == 0) nrm[row] = sqrt(s);
}

// ---- bf16-MFMA Gram, global_load_lds double-buffered, binarize + band-flag ----
// LDS content swizzled via PRE-SWIZZLED GLOBAL SOURCE (linear dest): linear slot g
// of row r holds global group g^(r&7); reads use the same involution.
__global__ __launch_bounds__(256) void kgram2(const ushort* __restrict__ xhi,
                                              const ushort* __restrict__ xlo,
                                              const double* __restrict__ nrm,
                                              uint32_t* __restrict__ bits,
                                              uint32_t* __restrict__ flagn,
                                              uint32_t* __restrict__ flags) {
  int flat = (int)blockIdx.x;
  int b = flat & 7;
  int tt = flat >> 3, I = 0;
  while (tt >= TTILES - I) { tt -= TTILES - I; ++I; }
  int J = I + tt;
  bool offdiag = (I != J);
  int c0 = I * 64, d0 = J * 64;
  int tid = threadIdx.x;
  int l = tid & 63, w = tid >> 6;
  int wc = w >> 1, wf = w & 1;
  int lg = l >> 4, li = l & 15;
  int rin = l >> 3, grp = l & 7;

  __shared__ ushort sm[2][16384];      // per buf: Ahi|Alo|Bhi|Blo @ 0/4096/8192/12288
  __shared__ uint32_t lb[64][2];
  __shared__ uint32_t lbT[64][2];

  const size_t xbase = (size_t)b * C_ * F_;

  auto stage = [&](int buf, int kc) {
#pragma unroll
    for (int i = 0; i < 8; ++i) {
      int c = w * 8 + i;                 // 0..31 chunks of 1KB
      int t = c >> 3, sub = c & 7;
      const ushort* src = (t & 1) ? xlo : xhi;
      int rbase = (t < 2) ? c0 : d0;
      int row = sub * 8 + rin;
      gload16(src + xbase + (size_t)(rbase + row) * F_ + kc * 64 + ((grp ^ rin) << 3),
              &sm[buf][t * 4096 + sub * 512]);
    }
  };

  f32x4 acc[2][2];
#pragma unroll
  for (int m = 0; m < 2; ++m)
#pragma unroll
    for (int n = 0; n < 2; ++n) acc[m][n] = (f32x4){0.f, 0.f, 0.f, 0.f};

  stage(0, 0);
  __syncthreads();
  for (int kc = 0; kc < 8; ++kc) {
    int buf = kc & 1;
    if (kc < 7) stage(buf ^ 1, kc + 1);
    const ushort* sb = sm[buf];
#pragma unroll
    for (int kk = 0; kk < 2; ++kk) {
      bf16x8 ah[2], al[2], bh[2], bl[2];
#pragma unroll
      for (int m = 0; m < 2; ++m) {
        int row = wc * 32 + m * 16 + li;
        int off = row * 64 + (((kk * 4 + lg) ^ (row & 7)) * 8);
        ah[m] = *reinterpret_cast<const bf16x8*>(&sb[off]);
        al[m] = *reinterpret_cast<const bf16x8*>(&sb[4096 + off]);
      }
#pragma unroll
      for (int n = 0; n < 2; ++n) {
        int row = wf * 32 + n * 16 + li;
        int off = row * 64 + (((kk * 4 + lg) ^ (row & 7)) * 8);
        bh[n] = *reinterpret_cast<const bf16x8*>(&sb[8192 + off]);
        bl[n] = *reinterpret_cast<const bf16x8*>(&sb[12288 + off]);
      }
#pragma unroll
      for (int m = 0; m < 2; ++m)
#pragma unroll
        for (int n = 0; n < 2; ++n) {
          acc[m][n] = __builtin_amdgcn_mfma_f32_16x16x32_bf16(ah[m], bh[n], acc[m][n], 0, 0, 0);
          acc[m][n] = __builtin_amdgcn_mfma_f32_16x16x32_bf16(ah[m], bl[n], acc[m][n], 0, 0, 0);
          acc[m][n] = __builtin_amdgcn_mfma_f32_16x16x32_bf16(al[m], bh[n], acc[m][n], 0, 0, 0);
        }
    }
    __syncthreads();
  }

  double ncv[2][4], ndv[2];
#pragma unroll
  for (int m = 0; m < 2; ++m)
#pragma unroll
    for (int q = 0; q < 4; ++q)
      ncv[m][q] = nrm[b * C_ + c0 + wc * 32 + m * 16 + lg * 4 + q];
#pragma unroll
  for (int n = 0; n < 2; ++n)
    ndv[n] = nrm[b * C_ + d0 + wf * 32 + n * 16 + li];

#pragma unroll
  for (int m = 0; m < 2; ++m) {
#pragma unroll
    for (int q = 0; q < 4; ++q) {
      uint32_t wv = 0;
#pragma unroll
      for (int n = 0; n < 2; ++n) {
        float num = acc[m][n][q];
        float tq = (float)(0.005 * ncv[m][q] * ndv[n]);
        bool bit = num > tq;
        if (fabsf(num - tq) < BAND) {
          uint32_t idx = atomicAdd(flagn, 1u);
          if (idx < FLAGCAP) {
            int cc = c0 + wc * 32 + m * 16 + lg * 4 + q;
            int dd = d0 + wf * 32 + n * 16 + li;
            flags[idx] = ((uint32_t)b << 22) | ((uint32_t)cc << 11) | (uint32_t)dd;
          }
        }
        unsigned long long bal = __ballot(bit);
        uint32_t b16 = (uint32_t)((bal >> (lg * 16)) & 0xFFFFull);
        wv |= b16 << (n * 16);
      }
      if (li == 0) lb[wc * 32 + m * 16 + lg * 4 + q][wf] = wv;
    }
  }
  __syncthreads();
  if (offdiag && tid < 64) {
    uint32_t w0 = 0, w1 = 0;
    int word = tid >> 5, sh = tid & 31;
    for (int c = 0; c < 32; ++c)  w0 |= ((lb[c][word] >> sh) & 1u) << c;
    for (int c = 32; c < 64; ++c) w1 |= ((lb[c][word] >> sh) & 1u) << (c - 32);
    lbT[tid][0] = w0; lbT[tid][1] = w1;
  }
  __syncthreads();
  if (tid < 64) {
    size_t base = ((size_t)b * C_ + c0 + tid) * 64 + (size_t)J * 2;
    bits[base] = lb[tid][0]; bits[base + 1] = lb[tid][1];
  } else if (offdiag && tid < 128) {
    int r = tid - 64;
    size_t base = ((size_t)b * C_ + d0 + r) * 64 + (size_t)I * 2;
    bits[base] = lbT[r][0]; bits[base + 1] = lbT[r][1];
  }
}

__global__ __launch_bounds__(256) void krepair(const float* __restrict__ x,
                                               const double* __restrict__ nrm,
                                               const uint32_t* __restrict__ flagn,
                                               const uint32_t* __restrict__ flags,
                                               uint32_t* __restrict__ bits) {
  int l = threadIdx.x & 63;
  uint32_t wave = (blockIdx.x * 256 + threadIdx.x) >> 6;
  uint32_t nwaves = (gridDim.x * 256) >> 6;
  uint32_t nf = *flagn; if (nf > FLAGCAP) nf = FLAGCAP;
  for (uint32_t p = wave; p < nf; p += nwaves) {
    uint32_t e = flags[p];
    int b = e >> 22, c = (e >> 11) & 2047, d = e & 2047;
    const float* xc = x + ((size_t)b * C_ + c) * F_;
    const float* xd = x + ((size_t)b * C_ + d) * F_;
    double s = 0.0;
#pragma unroll
    for (int j = 0; j < 8; ++j) {
      int k = l * 8 + j;
      s += (double)xc[k] * (double)xd[k];
    }
#pragma unroll
    for (int off = 32; off > 0; off >>= 1) s += __shfl_down(s, off, 64);
    if (l == 0) {
      bool bit = s > 0.005 * nrm[b * C_ + c] * nrm[b * C_ + d];
      uint32_t* wcd = bits + (((size_t)b * C_ + c) << 6) + (d >> 5);
      uint32_t* wdc = bits + (((size_t)b * C_ + d) << 6) + (c >> 5);
      uint32_t mcd = 1u << (d & 31), mdc = 1u << (c & 31);
      if (bit) { atomicOr(wcd, mcd);  atomicOr(wdc, mdc); }
      else     { atomicAnd(wcd, ~mcd); atomicAnd(wdc, ~mdc); }
    }
  }
}

__global__ __launch_bounds__(256) void kdeg(const uint32_t* __restrict__ bits,
                                            float* __restrict__ sinv) {
  int row = blockIdx.x * 256 + threadIdx.x;
  const uint4* p = reinterpret_cast<const uint4*>(bits + ((size_t)row << 6));
  uint32_t s = 0;
#pragma unroll
  for (int i = 0; i < 16; ++i) {
    uint4 v = p[i];
    s += __popc(v.x) + __popc(v.y) + __popc(v.z) + __popc(v.w);
  }
  sinv[row] = 1.0f / sqrtf((float)s);
}

// ---- split-bf16 MFMA GEMM, global_load_lds dbuf, LDS-transposed gT output ----
__global__ __launch_bounds__(256) void kgemm_mfma(const ushort* __restrict__ ahi,
                                                  const ushort* __restrict__ alo,
                                                  const ushort* __restrict__ wthi,
                                                  const ushort* __restrict__ wtlo,
                                                  const float* __restrict__ sinv,
                                                  ushort* __restrict__ gthi,
                                                  ushort* __restrict__ gtlo) {
  int flat = (int)blockIdx.x;
  int b = flat & 7, rest = flat >> 3;
  int mtl = rest & 31, nt = rest >> 5;
  int m0 = b * C_ + mtl * 64;
  int n0 = nt * 64;
  int tid = threadIdx.x;
  int l = tid & 63, w = tid >> 6;
  int wc = w >> 1, wf = w & 1;
  int lg = l >> 4, li = l & 15;
  int rin = l >> 3, grp = l & 7;

  __shared__ ushort sm[2][16384];      // per buf: Ahi|Alo|Whi|Wlo

  auto stage = [&](int buf, int kc) {
#pragma unroll
    for (int i = 0; i < 8; ++i) {
      int c = w * 8 + i;
      int t = c >> 3, sub = c & 7;
      int row = sub * 8 + rin;
      const ushort* src; size_t rb;
      if (t == 0)      { src = ahi;  rb = (size_t)(m0 + row) * F_; }
      else if (t == 1) { src = alo;  rb = (size_t)(m0 + row) * F_; }
      else if (t == 2) { src = wthi; rb = (size_t)(n0 + row) * F_; }
      else             { src = wtlo; rb = (size_t)(n0 + row) * F_; }
      gload16(src + rb + kc * 64 + ((grp ^ rin) << 3),
              &sm[buf][t * 4096 + sub * 512]);
    }
  };

  f32x4 acc[2][2];
#pragma unroll
  for (int m = 0; m < 2; ++m)
#pragma unroll
    for (int n = 0; n < 2; ++n) acc[m][n] = (f32x4){0.f, 0.f, 0.f, 0.f};

  stage(0, 0);
  __syncthreads();
  for (int kc = 0; kc < 8; ++kc) {
    int buf = kc & 1;
    if (kc < 7) stage(buf ^ 1, kc + 1);
    const ushort* sb = sm[buf];
#pragma unroll
    for (int kk = 0; kk < 2; ++kk) {
      bf16x8 ah[2], al[2], wh[2], wl[2];
#pragma unroll
      for (int m = 0; m < 2; ++m) {
        int row = wc * 32 + m * 16 + li;
        int off = row * 64 + (((kk * 4 + lg) ^ (row & 7)) * 8);
        ah[m] = *reinterpret_cast<const bf16x8*>(&sb[off]);
        al[m] = *reinterpret_cast<const bf16x8*>(&sb[4096 + off]);
      }
#pragma unroll
      for (int n = 0; n < 2; ++n) {
        int row = wf * 32 + n * 16 + li;
        int off = row * 64 + (((kk * 4 + lg) ^ (row & 7)) * 8);
        wh[n] = *reinterpret_cast<const bf16x8*>(&sb[8192 + off]);
        wl[n] = *reinterpret_cast<const bf16x8*>(&sb[12288 + off]);
      }
#pragma unroll
      for (int m = 0; m < 2; ++m)
#pragma unroll
        for (int n = 0; n < 2; ++n) {
          acc[m][n] = __builtin_amdgcn_mfma_f32_16x16x32_bf16(ah[m], wh[n], acc[m][n], 0, 0, 0);
          acc[m][n] = __builtin_amdgcn_mfma_f32_16x16x32_bf16(ah[m], wl[n], acc[m][n], 0, 0, 0);
          acc[m][n] = __builtin_amdgcn_mfma_f32_16x16x32_bf16(al[m], wh[n], acc[m][n], 0, 0, 0);
          acc[m][n] = __builtin_amdgcn_mfma_f32_16x16x32_bf16(al[m], wl[n], acc[m][n], 0, 0, 0);
        }
    }
    __syncthreads();
  }

  // epilogue: apply sinv, split, transpose via LDS (stride 72 = 16B aligned)
  ushort* tb = &sm[0][0];
#pragma unroll
  for (int m = 0; m < 2; ++m) {
    int dl = wc * 32 + m * 16 + lg * 4;
    f32x4 sc = *reinterpret_cast<const f32x4*>(&sinv[m0 + dl]);
#pragma unroll
    for (int n = 0; n < 2; ++n) {
      int fl = wf * 32 + n * 16 + li;
      ushort h4[4], l4[4];
#pragma unroll
      for (int q = 0; q < 4; ++q) {
        float v = sc[q] * acc[m][n][q];
        ushort hh = bf16hi(v);
        float hf = __bfloat162float(__builtin_bit_cast(__hip_bfloat16, hh));
        h4[q] = hh; l4[q] = bf16hi(v - hf);
      }
      *reinterpret_cast<ushort4*>(&tb[fl * 72 + dl])        = *reinterpret_cast<ushort4*>(h4);
      *reinterpret_cast<ushort4*>(&tb[4608 + fl * 72 + dl]) = *reinterpret_cast<ushort4*>(l4);
    }
  }
  __syncthreads();
  {
    int fl = tid >> 2, seg = tid & 3;
    int lo = fl * 72 + seg * 16;
    size_t ga = ((size_t)b * F_ + n0 + fl) * C_ + mtl * 64 + seg * 16;
    *reinterpret_cast<uint4*>(&gthi[ga])     = *reinterpret_cast<const uint4*>(&tb[lo]);
    *reinterpret_cast<uint4*>(&gthi[ga + 8]) = *reinterpret_cast<const uint4*>(&tb[lo + 8]);
    *reinterpret_cast<uint4*>(&gtlo[ga])     = *reinterpret_cast<const uint4*>(&tb[4608 + lo]);
    *reinterpret_cast<uint4*>(&gtlo[ga + 8]) = *reinterpret_cast<const uint4*>(&tb[4608 + lo + 8]);
  }
}

// ---- MFMA propagation, 128c x 64f tile, global_load_lds dbuf ----
__global__ __launch_bounds__(256) void kprop_mfma(const ushort* __restrict__ gthi,
                                                  const ushort* __restrict__ gtlo,
                                                  const float* __restrict__ sinv,
                                                  const uint32_t* __restrict__ bits,
                                                  const float* __restrict__ bias,
                                                  ushort* __restrict__ ohi,
                                                  ushort* __restrict__ olo,
                                                  float* __restrict__ of32) {
  int flat = (int)blockIdx.x;
  int b = flat & 7, rest = flat >> 3;
  int ct = rest & 15, ft = rest >> 4;
  int c0 = ct * 128, f0 = ft * 64;
  int tid = threadIdx.x;
  int l = tid & 63, w = tid >> 6;
  int lg = l >> 4, li = l & 15;
  int rin = l >> 3, grp = l & 7;
  int w32 = w * 32;

  __shared__ ushort smv[2][8192];      // per buf: vThi | vTlo (4096 each)
  __shared__ uint32_t blds[128][68];

  const uint32_t* bp = bits + (((size_t)b * C_ + c0) << 6);
#pragma unroll
  for (int t = 0; t < 8; ++t) {
    int gi = (t * 256 + tid) * 4;
    uint4 q = *reinterpret_cast<const uint4*>(bp + gi);
    int row = gi >> 6, col = gi & 63;
    *reinterpret_cast<uint4*>(&blds[row][col]) = q;
  }

  auto stage = [&](int buf, int dd) {
#pragma unroll
    for (int i = 0; i < 4; ++i) {
      int c = w * 4 + i;                 // 0..15 chunks
      int t = c >> 3, sub = c & 7;
      const ushort* src = t ? gtlo : gthi;
      int row = f0 + sub * 8 + rin;
      gload16(src + ((size_t)b * F_ + row) * C_ + dd + ((grp ^ rin) << 3),
              &smv[buf][t * 4096 + sub * 512]);
    }
  };

  f32x4 acc[2][4];
#pragma unroll
  for (int m = 0; m < 2; ++m)
#pragma unroll
    for (int n = 0; n < 4; ++n) acc[m][n] = (f32x4){0.f, 0.f, 0.f, 0.f};

  stage(0, 0);
  __syncthreads();
  for (int ch = 0; ch < 32; ++ch) {
    int buf = ch & 1;
    if (ch < 31) stage(buf ^ 1, (ch + 1) * 64);
    const ushort* sb = smv[buf];
    int wbase = ch * 2;
#pragma unroll
    for (int kk = 0; kk < 2; ++kk) {
      uint32_t wd0 = blds[w32 + li][wbase + kk];
      uint32_t wd1 = blds[w32 + 16 + li][wbase + kk];
      uint32_t by0 = (wd0 >> (lg * 8)) & 0xFFu;
      uint32_t by1 = (wd1 >> (lg * 8)) & 0xFFu;
      bf16x8 a0, a1;
#pragma unroll
      for (int j = 0; j < 8; ++j) {
        a0[j] = (short)(((by0 >> j) & 1u) ? 0x3F80 : 0);
        a1[j] = (short)(((by1 >> j) & 1u) ? 0x3F80 : 0);
      }
#pragma unroll
      for (int n = 0; n < 4; ++n) {
        int row = n * 16 + li;
        int off = row * 64 + (((kk * 4 + lg) ^ (row & 7)) * 8);
        bf16x8 bh = *reinterpret_cast<const bf16x8*>(&sb[off]);
        bf16x8 bl = *reinterpret_cast<const bf16x8*>(&sb[4096 + off]);
        acc[0][n] = __builtin_amdgcn_mfma_f32_16x16x32_bf16(a0, bh, acc[0][n], 0, 0, 0);
        acc[0][n] = __builtin_amdgcn_mfma_f32_16x16x32_bf16(a0, bl, acc[0][n], 0, 0, 0);
        acc[1][n] = __builtin_amdgcn_mfma_f32_16x16x32_bf16(a1, bh, acc[1][n], 0, 0, 0);
        acc[1][n] = __builtin_amdgcn_mfma_f32_16x16x32_bf16(a1, bl, acc[1][n], 0, 0, 0);
      }
    }
    __syncthreads();
  }

  const float* sv = sinv + b * C_;
  float bb = bias[0];
#pragma unroll
  for (int m = 0; m < 2; ++m) {
    int rowb = c0 + w32 + m * 16 + lg * 4;
    f32x4 sc = *reinterpret_cast<const f32x4*>(&sv[rowb]);
#pragma unroll
    for (int n = 0; n < 4; ++n) {
      int col = f0 + n * 16 + li;
      if (of32) {
#pragma unroll
        for (int q = 0; q < 4; ++q) {
          float o = fmaxf(sc[q] * acc[m][n][q] + bb, 0.f);
          of32[((size_t)b * C_ + rowb + q) * F_ + col] = o;
        }
      } else {
#pragma unroll
        for (int q = 0; q < 4; ++q) {
          float o = fmaxf(sc[q] * acc[m][n][q] + bb, 0.f);
          ushort hh = bf16hi(o);
          float hf = __bfloat162float(__builtin_bit_cast(__hip_bfloat16, hh));
          size_t ga = ((size_t)b * C_ + rowb + q) * F_ + col;
          ohi[ga] = hh;
          olo[ga] = bf16hi(o - hf);
        }
      }
    }
  }
}

extern "C" void kernel_launch(void* const* d_in, const int* in_sizes, int n_in,
                              void* d_out, int out_size, void* d_ws, size_t ws_size,
                              hipStream_t stream) {
  (void)in_sizes; (void)n_in; (void)out_size; (void)ws_size;
  const float* x  = (const float*)d_in[0];
  const float* W1 = (const float*)d_in[1];
  const float* b1 = (const float*)d_in[2];
  const float* W2 = (const float*)d_in[3];
  const float* b2 = (const float*)d_in[4];
  float* out = (float*)d_out;

  char* ws = (char*)d_ws;
  double*   nrm   = (double*)(ws);
  uint32_t* bits  = (uint32_t*)(ws + 131072);
  float*    sinv  = (float*)(ws + 4325376);
  uint32_t* flagn = (uint32_t*)(ws + 4390912);
  uint32_t* flags = (uint32_t*)(ws + 4391168);
  ushort*   wt    = (ushort*)(ws + 5439744);
  ushort*   xhi   = (ushort*)(ws + 7536896);
  ushort*   xlo   = (ushort*)(ws + 24314112);
  ushort*   gthi  = (ushort*)(ws + 41091328);
  ushort*   gtlo  = (ushort*)(ws + 57868544);
  ushort*   wt1hi = wt, *wt1lo = wt + 262144, *wt2hi = wt + 524288, *wt2lo = wt + 786432;

  kzero1<<<dim3(1), 64, 0, stream>>>(flagn);
  ksplit<<<dim3(B_ * C_ * F_ / 2048), 256, 0, stream>>>(x, xhi, xlo);
  knorm<<<dim3(B_ * C_ / 4), 256, 0, stream>>>(x, nrm);
  kwsplit<<<dim3(8, 8, 2), 256, 0, stream>>>(W1, W2, wt);
  kgram2<<<dim3(NPAIRS * B_), 256, 0, stream>>>(xhi, xlo, nrm, bits, flagn, flags);
  krepair<<<dim3(256), 256, 0, stream>>>(x, nrm, flagn, flags, bits);
  kdeg<<<dim3(B_ * C_ / 256), 256, 0, stream>>>(bits, sinv);

  // layer 1
  kgemm_mfma<<<dim3(2048), 256, 0, stream>>>(xhi, xlo, wt1hi, wt1lo, sinv, gthi, gtlo);
  kprop_mfma<<<dim3(1024), 256, 0, stream>>>(gthi, gtlo, sinv, bits, b1, xhi, xlo, nullptr);
  // layer 2
  kgemm_mfma<<<dim3(2048), 256, 0, stream>>>(xhi, xlo, wt2hi, wt2lo, sinv, gthi, gtlo);
  kprop_mfma<<<dim3(1024), 256, 0, stream>>>(gthi, gtlo, sinv, bits, b2, nullptr, nullptr, out);
}